// Round 1
// baseline (96.067 us; speedup 1.0000x reference)
//
#include <hip/hip_runtime.h>

typedef unsigned short u16;
typedef unsigned int u32;
typedef __attribute__((ext_vector_type(8))) short short8;
typedef __attribute__((ext_vector_type(4))) float f32x4;
typedef __attribute__((ext_vector_type(4))) unsigned short ushort4v;
typedef __attribute__((ext_vector_type(4))) float float4v;

// ---------- helpers ----------
__device__ __forceinline__ float bf2f(u16 u) {
    return __uint_as_float(((u32)u) << 16);
}
__device__ __forceinline__ u16 f2bf(float f) {
    u32 u = __float_as_uint(f);
    u += 0x7FFF + ((u >> 16) & 1);   // RNE
    return (u16)(u >> 16);
}

// ---------- K0: fp32 -> bf16 convert ----------
__global__ __launch_bounds__(256) void cvt_bf16(const float* __restrict__ in,
                                                u16* __restrict__ out, int n4) {
    int i = blockIdx.x * 256 + threadIdx.x;
    int stride = gridDim.x * 256;
    for (; i < n4; i += stride) {
        float4v v = ((const float4v*)in)[i];
        ushort4v r;
        r[0] = f2bf(v[0]); r[1] = f2bf(v[1]); r[2] = f2bf(v[2]); r[3] = f2bf(v[3]);
        ((ushort4v*)out)[i] = r;
    }
}

// ---------- K1: qkv = x @ W^T, bf16 MFMA, 128x128 tile, BK=32 ----------
// A = xb [16384][512] (K-major), BT = wb [1536][512] (K-major), C = qkv bf16 [16384][1536]
__global__ __launch_bounds__(256) void gemm_qkv(const u16* __restrict__ xb,
                                                const u16* __restrict__ wb,
                                                u16* __restrict__ qkv) {
    __shared__ u16 As[128 * 32];
    __shared__ u16 Bs[128 * 32];
    const int t = threadIdx.x;
    const int m0 = blockIdx.x * 128;
    const int n0 = blockIdx.y * 128;
    const int l = t & 63, w = t >> 6;
    const int wm = (w >> 1) * 64, wn = (w & 1) * 64;
    const int lr = l & 15, lk = (l >> 4) * 8;
    // staging: thread t loads 16B: row sr (and sr+64), cols sc..sc+8
    const int sr = t >> 2, sc = (t & 3) * 8;
    const u16* ag = xb + (size_t)(m0 + sr) * 512 + sc;
    const u16* bg = wb + (size_t)(n0 + sr) * 512 + sc;

    f32x4 zz = {0.f, 0.f, 0.f, 0.f};
    f32x4 acc[4][4];
    for (int i = 0; i < 4; ++i)
        for (int j = 0; j < 4; ++j) acc[i][j] = zz;

    for (int k0 = 0; k0 < 512; k0 += 32) {
        int4 a0 = *(const int4*)(ag + k0);
        int4 a1 = *(const int4*)(ag + 64 * 512 + k0);
        int4 b0 = *(const int4*)(bg + k0);
        int4 b1 = *(const int4*)(bg + 64 * 512 + k0);
        __syncthreads();
        *(int4*)(As + sr * 32 + sc) = a0;
        *(int4*)(As + (sr + 64) * 32 + sc) = a1;
        *(int4*)(Bs + sr * 32 + sc) = b0;
        *(int4*)(Bs + (sr + 64) * 32 + sc) = b1;
        __syncthreads();
        short8 af[4], bfr[4];
#pragma unroll
        for (int mi = 0; mi < 4; ++mi)
            af[mi] = *(const short8*)(As + (wm + mi * 16 + lr) * 32 + lk);
#pragma unroll
        for (int ni = 0; ni < 4; ++ni)
            bfr[ni] = *(const short8*)(Bs + (wn + ni * 16 + lr) * 32 + lk);
#pragma unroll
        for (int mi = 0; mi < 4; ++mi)
#pragma unroll
            for (int ni = 0; ni < 4; ++ni)
                acc[mi][ni] = __builtin_amdgcn_mfma_f32_16x16x32_bf16(
                    af[mi], bfr[ni], acc[mi][ni], 0, 0, 0);
    }
    // epilogue: D col = lane&15, row = (lane>>4)*4 + reg
#pragma unroll
    for (int mi = 0; mi < 4; ++mi)
#pragma unroll
        for (int ni = 0; ni < 4; ++ni) {
            int col = n0 + wn + ni * 16 + lr;
#pragma unroll
            for (int j = 0; j < 4; ++j) {
                int row = m0 + wm + mi * 16 + (l >> 4) * 4 + j;
                qkv[(size_t)row * 1536 + col] = f2bf(acc[mi][ni][j]);
            }
        }
}

// ---------- K2a: per (b,h) partial G0 = k^T v, ksum, vsum over 256-row slices ----------
// grid = 16 bh * 32 splits; block 256
__global__ __launch_bounds__(256) void kv_outer(const u16* __restrict__ qkv,
                                                float* __restrict__ gpart,
                                                float* __restrict__ ksump,
                                                float* __restrict__ vsump) {
    const int bh = blockIdx.x >> 5, s = blockIdx.x & 31;
    const int b = bh >> 3, h = bh & 7;
    const int t = threadIdx.x;
    const int tx = t & 15, ty = t >> 4;
    __shared__ u16 ks[64 * 64];
    __shared__ u16 vs[64 * 64];
    const u16* kg = qkv + ((size_t)(b * 8192 + s * 256)) * 1536 + 512 + h * 64;
    const u16* vg = kg + 512;
    const int sr = t >> 3, sc = (t & 7) * 8;

    float acc[4][4];
    for (int i = 0; i < 4; ++i)
        for (int j = 0; j < 4; ++j) acc[i][j] = 0.f;
    float ka[4] = {0.f, 0.f, 0.f, 0.f}, va[4] = {0.f, 0.f, 0.f, 0.f};

    for (int c = 0; c < 4; ++c) {
        const u16* kgc = kg + (size_t)(c * 64 + sr) * 1536 + sc;
        const u16* vgc = vg + (size_t)(c * 64 + sr) * 1536 + sc;
        int4 k0v = *(const int4*)kgc;
        int4 k1v = *(const int4*)(kgc + (size_t)32 * 1536);
        int4 v0v = *(const int4*)vgc;
        int4 v1v = *(const int4*)(vgc + (size_t)32 * 1536);
        __syncthreads();
        *(int4*)(ks + sr * 64 + sc) = k0v;
        *(int4*)(ks + (sr + 32) * 64 + sc) = k1v;
        *(int4*)(vs + sr * 64 + sc) = v0v;
        *(int4*)(vs + (sr + 32) * 64 + sc) = v1v;
        __syncthreads();
#pragma unroll 4
        for (int n = 0; n < 64; ++n) {
            ushort4v k4 = *(const ushort4v*)(ks + n * 64 + ty * 4);
            ushort4v v4 = *(const ushort4v*)(vs + n * 64 + tx * 4);
            float kf[4], vf[4];
#pragma unroll
            for (int i = 0; i < 4; ++i) { kf[i] = bf2f(k4[i]); vf[i] = bf2f(v4[i]); }
#pragma unroll
            for (int i = 0; i < 4; ++i)
#pragma unroll
                for (int j = 0; j < 4; ++j) acc[i][j] += kf[i] * vf[j];
#pragma unroll
            for (int i = 0; i < 4; ++i) { ka[i] += kf[i]; va[i] += vf[i]; }
        }
    }
    size_t gb = ((size_t)(bh * 32 + s)) * 4096;
#pragma unroll
    for (int i = 0; i < 4; ++i)
#pragma unroll
        for (int j = 0; j < 4; ++j)
            gpart[gb + (ty * 4 + i) * 64 + tx * 4 + j] = acc[i][j];
    if (tx == 0)
        for (int i = 0; i < 4; ++i) ksump[(bh * 32 + s) * 64 + ty * 4 + i] = ka[i];
    if (ty == 0)
        for (int i = 0; i < 4; ++i) vsump[(bh * 32 + s) * 64 + tx * 4 + i] = va[i];
}

// ---------- K2b: reduce partials, apply mean-centering correction, write g^T bf16 ----------
// grid = 16 bh * 16 parts; block 256 (one entry per thread)
__global__ __launch_bounds__(256) void g_final(const float* __restrict__ gpart,
                                               const float* __restrict__ ksump,
                                               const float* __restrict__ vsump,
                                               u16* __restrict__ gt) {
    const int bh = blockIdx.x >> 4, part = blockIdx.x & 15;
    const int t = threadIdx.x;
    __shared__ float kls[64], vls[64];
    if (t < 64) {
        float s = 0.f;
        for (int j = 0; j < 32; ++j) s += ksump[(bh * 32 + j) * 64 + t];
        kls[t] = s;
    } else if (t < 128) {
        int d = t - 64;
        float s = 0.f;
        for (int j = 0; j < 32; ++j) s += vsump[(bh * 32 + j) * 64 + d];
        vls[d] = s;
    }
    __syncthreads();
    const int idx = part * 256 + t;
    const int d1 = idx >> 6, d2 = idx & 63;
    float s = 0.f;
    for (int j = 0; j < 32; ++j) s += gpart[((size_t)(bh * 32 + j)) * 4096 + idx];
    s -= kls[d1] * vls[d2] * (1.0f / 8192.0f);
    gt[bh * 4096 + d2 * 64 + d1] = f2bf(s);   // store transposed (B^T layout for K3)
}

// ---------- K3: z = (scale + q @ g) / (N*scale), MFMA M=8192,N=64,K=64 per bh ----------
// grid = 16 bh * 64 chunks (128 rows each); block 256 = 4 waves * 32 rows
__global__ __launch_bounds__(256) void out_z(const u16* __restrict__ qkv,
                                             const u16* __restrict__ gt,
                                             float* __restrict__ z) {
    const int bh = blockIdx.x >> 6, chunk = blockIdx.x & 63;
    const int b = bh >> 3, h = bh & 7;
    const int t = threadIdx.x, l = t & 63, w = t >> 6;
    const int lr = l & 15, lk = (l >> 4) * 8;
    const u16* qcol = qkv + ((size_t)b * 8192) * 1536 + h * 64;
    const u16* gb = gt + bh * 4096;

    short8 bfr[2][4];
#pragma unroll
    for (int kk = 0; kk < 2; ++kk)
#pragma unroll
        for (int ni = 0; ni < 4; ++ni)
            bfr[kk][ni] = *(const short8*)(gb + (ni * 16 + lr) * 64 + kk * 32 + lk);

    f32x4 zz = {0.f, 0.f, 0.f, 0.f};
    f32x4 acc[2][4];
    for (int i = 0; i < 2; ++i)
        for (int j = 0; j < 4; ++j) acc[i][j] = zz;

    const int r0 = chunk * 128 + w * 32;
#pragma unroll
    for (int kk = 0; kk < 2; ++kk)
#pragma unroll
        for (int mi = 0; mi < 2; ++mi) {
            short8 af = *(const short8*)(qcol + (size_t)(r0 + mi * 16 + lr) * 1536 + kk * 32 + lk);
#pragma unroll
            for (int ni = 0; ni < 4; ++ni)
                acc[mi][ni] = __builtin_amdgcn_mfma_f32_16x16x32_bf16(
                    af, bfr[kk][ni], acc[mi][ni], 0, 0, 0);
        }

    const float sc = 0.125f;           // d^-0.5
    const float inv = 1.0f / 1024.0f;  // 1 / (N*scale)
#pragma unroll
    for (int mi = 0; mi < 2; ++mi)
#pragma unroll
        for (int ni = 0; ni < 4; ++ni) {
            int col = ni * 16 + lr;
#pragma unroll
            for (int j = 0; j < 4; ++j) {
                int row = r0 + mi * 16 + (l >> 4) * 4 + j;
                z[((size_t)bh * 8192 + row) * 64 + col] = (sc + acc[mi][ni][j]) * inv;
            }
        }
}

extern "C" void kernel_launch(void* const* d_in, const int* in_sizes, int n_in,
                              void* d_out, int out_size, void* d_ws, size_t ws_size,
                              hipStream_t stream) {
    const float* x = (const float*)d_in[0];   // [2,8192,512] fp32
    const float* W = (const float*)d_in[1];   // [1536,512] fp32
    float* z = (float*)d_out;                 // [2,8,8192,64] fp32

    char* ws = (char*)d_ws;
    u16* xb    = (u16*)(ws);                        // 16,777,216 B
    u16* wb    = (u16*)(ws + 16777216);             //  1,572,864 B
    u16* qkv   = (u16*)(ws + 18350080);             // 50,331,648 B
    float* gpart = (float*)(ws + 68681728);         //  8,388,608 B (16*32*4096 f32)
    float* ksump = (float*)(ws + 77070336);         //    131,072 B
    float* vsump = (float*)(ws + 77201408);         //    131,072 B
    u16* gt    = (u16*)(ws + 77332480);             //    131,072 B

    cvt_bf16<<<2048, 256, 0, stream>>>(x, xb, 8388608 / 4);
    cvt_bf16<<<384, 256, 0, stream>>>(W, wb, 786432 / 4);
    gemm_qkv<<<dim3(128, 12), 256, 0, stream>>>(xb, wb, qkv);
    kv_outer<<<512, 256, 0, stream>>>(qkv, gpart, ksump, vsump);
    g_final<<<256, 256, 0, stream>>>(gpart, ksump, vsump, gt);
    out_z<<<1024, 256, 0, stream>>>(qkv, gt, z);
}